// Round 1
// baseline (623.109 us; speedup 1.0000x reference)
//
#include <hip/hip_runtime.h>

// KPN (kernel-predicting network) fused kernel, fp32 correctness-first version.
// out[n,c,h,w] = sum_u softmax_u(conv3x3(x)[n, c*25+u, h, w]) * x_pad[n,c,h+u/5-2,w+u%5-2]

#define KW 5
#define KK 25
#define KKP 28            // 25 padded to 28 for b128-friendly LDS rows
#define C_IN 16
#define RK 144            // C_IN * 3 * 3

constexpr int TH = 8, TW = 32;        // pixel tile per block
constexpr int XH = TH + 4;            // 12 (halo 2 each side)
constexpr int XW = TW + 4;            // 36

__global__ __launch_bounds__(256) void kpn_fp32_kernel(
    const float* __restrict__ x, const float* __restrict__ cw,
    const float* __restrict__ cb, float* __restrict__ out,
    int N, int H, int W)
{
  const int nc = blockIdx.z;
  const int n = nc / C_IN;
  const int c = nc % C_IN;
  const int h0 = blockIdx.y * TH;
  const int w0 = blockIdx.x * TW;

  __shared__ float xt[C_IN][XH][XW];   // 16*12*36*4 = 27648 B
  __shared__ float wt[RK][KKP];        // 144*28*4  = 16128 B
  __shared__ float bt[KK];

  const int tid = threadIdx.x;

  // ---- stage x tile (all input channels, halo 2, zero-padded OOB) ----
  const int xtot = C_IN * XH * XW;     // 6912 = 27 * 256
  for (int i = tid; i < xtot; i += 256) {
    int ci  = i / (XH * XW);
    int r   = (i / XW) % XH;
    int col = i % XW;
    int gh = h0 + r - 2, gw = w0 + col - 2;
    float v = 0.f;
    if (gh >= 0 && gh < H && gw >= 0 && gw < W)
      v = x[((n * C_IN + ci) * H + gh) * W + gw];
    xt[ci][r][col] = v;
  }
  // ---- stage weights for this c, transposed to [kpos][u] ----
  for (int i = tid; i < RK * KKP; i += 256) {
    int kpos = i / KKP;
    int u    = i % KKP;
    float v = 0.f;
    if (u < KK) v = cw[(c * KK + u) * RK + kpos];
    wt[kpos][u] = v;
  }
  if (tid < KK) bt[tid] = cb[c * KK + tid];
  __syncthreads();

  const int ty = tid >> 5;        // 0..7   (TW == 32)
  const int tx = tid & 31;        // 0..31

  // ---- conv: 25 logits for this pixel ----
  float acc[KK];
  #pragma unroll
  for (int u = 0; u < KK; ++u) acc[u] = bt[u];

  for (int ci = 0; ci < C_IN; ++ci) {
    #pragma unroll
    for (int kh = 0; kh < 3; ++kh) {
      #pragma unroll
      for (int kw = 0; kw < 3; ++kw) {
        // conv needs x[h+kh-1, w+kw-1]; tile origin is (h0-2, w0-2)
        float xv = xt[ci][ty + 1 + kh][tx + 1 + kw];
        const float* wrow = &wt[ci * 9 + kh * 3 + kw][0];
        #pragma unroll
        for (int u = 0; u < KK; ++u) acc[u] += xv * wrow[u];
      }
    }
  }

  // ---- softmax over the 25 window positions ----
  float m = acc[0];
  #pragma unroll
  for (int u = 1; u < KK; ++u) m = fmaxf(m, acc[u]);
  float s = 0.f;
  #pragma unroll
  for (int u = 0; u < KK; ++u) { acc[u] = __expf(acc[u] - m); s += acc[u]; }
  const float inv = 1.f / s;

  // ---- weighted sum over the 5x5 unfold window (channel c only) ----
  float o = 0.f;
  #pragma unroll
  for (int i = 0; i < KW; ++i)
    #pragma unroll
    for (int j = 0; j < KW; ++j)
      o += xt[c][ty + i][tx + j] * acc[i * KW + j];
  o *= inv;

  out[((n * C_IN + c) * H + (h0 + ty)) * W + (w0 + tx)] = o;
}

extern "C" void kernel_launch(void* const* d_in, const int* in_sizes, int n_in,
                              void* d_out, int out_size, void* d_ws, size_t ws_size,
                              hipStream_t stream) {
  const float* x  = (const float*)d_in[0];
  const float* cw = (const float*)d_in[1];
  const float* cb = (const float*)d_in[2];
  float* out = (float*)d_out;

  const int N = 4, H = 256, W = 256;
  dim3 grid(W / TW, H / TH, N * C_IN);   // (8, 32, 64)
  kpn_fp32_kernel<<<grid, 256, 0, stream>>>(x, cw, cb, out, N, H, W);
}

// Round 2
// 161.453 us; speedup vs baseline: 3.8594x; 3.8594x over previous
//
#include <hip/hip_runtime.h>

// KPN fused kernel, round 2: implicit-GEMM conv via mfma_f32_32x32x16_bf16.
//
// Per channel c: logits[u=0..24][pixel] = sum_k W[c*25+u, k] * patch[k, pixel],
// K = 144 ordered (kh,kw,ci) -> 9 MFMA K-steps of 16 (one conv tap each).
// A (weights) prepacked to fragment order, read straight from L2.
// B (patches) = ds_read_b128 from channel-last LDS x-tile.
// Softmax over u done in-lane on the D fragment (+1 shfl_xor(32)).
// Weighted 5x5 window sum reads a padded-pitch channel-last tile, 2 c's per b32.

typedef __bf16 bf16x8 __attribute__((ext_vector_type(8)));
typedef float  f32x16 __attribute__((ext_vector_type(16)));

#define C_IN 16
#define IMG  256

__device__ __forceinline__ unsigned short f2bf(float f) {
  union { float f; unsigned int u; } v; v.f = f;
  unsigned int u = v.u;
  return (unsigned short)((u + 0x7FFFu + ((u >> 16) & 1u)) >> 16);  // RNE
}

// ---------------- prepack: weights+bias -> MFMA fragment order ----------------
// apk[c][pos][lane][j] (bf16): A-frag for (c,pos): row m = lane&31 (>=25 -> 0),
//   k-local ci = 8*(lane>>5)+j.   pos = kh*3+kw.
// pb[c][lane][reg] (f32): bias at D position row=(reg&3)+8*(reg>>2)+4*(lane>>5).
__global__ __launch_bounds__(256) void kpn_prepack(
    const float* __restrict__ cw, const float* __restrict__ cb,
    unsigned short* __restrict__ apk, float* __restrict__ pb)
{
  int t = blockIdx.x * 256 + threadIdx.x;
  if (t < 16 * 9 * 64 * 8) {
    int j = t & 7, lane = (t >> 3) & 63, rest = t >> 9;
    int pos = rest % 9, c = rest / 9;
    int m = lane & 31, g = lane >> 5, ci = g * 8 + j;
    float v = (m < 25) ? cw[((c * 25 + m) * 16 + ci) * 9 + pos] : 0.f;
    apk[t] = f2bf(v);
  }
  if (t < 16 * 64 * 16) {
    int r = t & 15, lane = (t >> 4) & 63, c = t >> 10;
    int g = lane >> 5;
    int row = (r & 3) + 8 * (r >> 2) + 4 * g;
    pb[t] = (row < 25) ? cb[c * 25 + row] : 0.f;
  }
}

// ---------------- main fused kernel ----------------
__global__ __launch_bounds__(256, 2) void kpn_mfma_kernel(
    const float* __restrict__ x,
    const unsigned short* __restrict__ apk,
    const float* __restrict__ pb,
    float* __restrict__ out)
{
  // LDS x tiles, halo 2 each side (block pixel tile 16x16 -> 20x20 positions)
  __shared__ unsigned short xcl[20][20][16];  // channel-last, pitch 32 B: b128 B-frags
  __shared__ unsigned short xep[20][20][18];  // padded pitch 36 B: conflict-free epi reads

  const int tid  = threadIdx.x;
  const int w0   = blockIdx.x * 16;
  const int h0   = blockIdx.y * 16;
  const int nimg = blockIdx.z;

  // ---- stage x tile (f32 global -> bf16 LDS, both layouts), zero-pad OOB ----
  for (int i = tid; i < 16 * 400; i += 256) {
    int ci = i / 400, p = i % 400;
    int rr = p / 20, cc = p % 20;
    int gh = h0 + rr - 2, gw = w0 + cc - 2;
    float v = 0.f;
    if (gh >= 0 && gh < IMG && gw >= 0 && gw < IMG)
      v = x[((nimg * C_IN + ci) * IMG + gh) * IMG + gw];
    unsigned short b = f2bf(v);
    xcl[rr][cc][ci] = b;
    xep[rr][cc][ci] = b;
  }
  __syncthreads();

  const int wave  = tid >> 6;          // 0..3 -> block rows 4w..4w+3
  const int lane  = tid & 63;
  const int g     = lane >> 5;         // fragment half
  const bool g0   = (g == 0);
  const int n32   = lane & 31;         // pixel within 32-tile
  const int px    = n32 & 15;          // pixel col in block
  const int py_in = n32 >> 4;          // 0/1
  const int wrow0 = wave * 4;

  // ---- per-reg epilogue window offsets (byte offsets into xep) ----
  int offs[13];
#pragma unroll
  for (int r = 0; r < 13; ++r) {
    int row = 4 * g + (r & 3) + 8 * (r >> 2);
    int du = row / 5, dv = row % 5;
    offs[r] = (row < 25) ? ((du * 20 + dv) * 36) : 0;   // invalid -> safe addr, weight 0
  }

  // ---- preload B-fragments (patches) for this wave's 2 n-tiles x 9 taps ----
  bf16x8 bfr[2][9];
#pragma unroll
  for (int nt = 0; nt < 2; ++nt) {
    int py = wrow0 + nt * 2 + py_in;
#pragma unroll
    for (int pos = 0; pos < 9; ++pos) {
      int kh = pos / 3, kw = pos % 3;
      bfr[nt][pos] = *reinterpret_cast<const bf16x8*>(&xcl[py + 1 + kh][px + 1 + kw][g * 8]);
    }
  }

  const bf16x8* apv = reinterpret_cast<const bf16x8*>(apk);
  const f32x16* pbv = reinterpret_cast<const f32x16*>(pb);
  const char*   xepb = reinterpret_cast<const char*>(&xep[0][0][0]);

  const int pbase0 = ((wrow0 + py_in) * 20 + px) * 36;       // nt=0 pixel byte base
  const int pbase1 = ((wrow0 + 2 + py_in) * 20 + px) * 36;   // nt=1

  // epilogue for one n-tile, one c-pair (A0: c0, A1: c0+1)
  auto epi = [&](f32x16 A0, f32x16 A1, int c0, int pbase, int hrow) {
    float m0 = -3e38f, m1 = -3e38f;
#pragma unroll
    for (int r = 0; r < 12; ++r) { m0 = fmaxf(m0, A0[r]); m1 = fmaxf(m1, A1[r]); }
    m0 = fmaxf(m0, g0 ? A0[12] : -3e38f);
    m1 = fmaxf(m1, g0 ? A1[12] : -3e38f);
    m0 = fmaxf(m0, __shfl_xor(m0, 32));
    m1 = fmaxf(m1, __shfl_xor(m1, 32));
    float s0 = 0.f, s1 = 0.f;
#pragma unroll
    for (int r = 0; r < 12; ++r) {
      float e0 = __expf(A0[r] - m0), e1 = __expf(A1[r] - m1);
      A0[r] = e0; A1[r] = e1; s0 += e0; s1 += e1;
    }
    {
      float e0 = g0 ? __expf(A0[12] - m0) : 0.f;
      float e1 = g0 ? __expf(A1[12] - m1) : 0.f;
      A0[12] = e0; A1[12] = e1; s0 += e0; s1 += e1;
    }
    s0 += __shfl_xor(s0, 32);
    s1 += __shfl_xor(s1, 32);
    float ws0 = 0.f, ws1 = 0.f;
    const int base = pbase + c0 * 2;
#pragma unroll
    for (int r = 0; r < 13; ++r) {
      unsigned int u = *reinterpret_cast<const unsigned int*>(xepb + base + offs[r]);
      union { unsigned int u; float f; } lo, hi;
      lo.u = u << 16; hi.u = u & 0xFFFF0000u;    // bf16 c0 (low), c0+1 (high)
      ws0 = fmaf(A0[r], lo.f, ws0);
      ws1 = fmaf(A1[r], hi.f, ws1);
    }
    ws0 += __shfl_xor(ws0, 32);
    ws1 += __shfl_xor(ws1, 32);
    int   cc  = g0 ? c0 : (c0 + 1);
    float val = g0 ? (ws0 / s0) : (ws1 / s1);
    out[((nimg * C_IN + cc) * IMG + hrow) * IMG + (w0 + px)] = val;
  };

  // ---- c-pair loop: 9-step MFMA GEMM + fused softmax/window epilogue ----
  for (int cp = 0; cp < 8; ++cp) {
    const int c0 = cp * 2;
    f32x16 b0 = pbv[c0 * 64 + lane];
    f32x16 b1 = pbv[(c0 + 1) * 64 + lane];
    f32x16 a00 = b0, a01 = b0, a10 = b1, a11 = b1;   // [c][ntile]
#pragma unroll
    for (int pos = 0; pos < 9; ++pos) {
      bf16x8 wf0 = apv[(c0 * 9 + pos) * 64 + lane];
      bf16x8 wf1 = apv[((c0 + 1) * 9 + pos) * 64 + lane];
      a00 = __builtin_amdgcn_mfma_f32_32x32x16_bf16(wf0, bfr[0][pos], a00, 0, 0, 0);
      a01 = __builtin_amdgcn_mfma_f32_32x32x16_bf16(wf0, bfr[1][pos], a01, 0, 0, 0);
      a10 = __builtin_amdgcn_mfma_f32_32x32x16_bf16(wf1, bfr[0][pos], a10, 0, 0, 0);
      a11 = __builtin_amdgcn_mfma_f32_32x32x16_bf16(wf1, bfr[1][pos], a11, 0, 0, 0);
    }
    epi(a00, a10, c0, pbase0, h0 + wrow0 + py_in);
    epi(a01, a11, c0, pbase1, h0 + wrow0 + 2 + py_in);
  }
}

extern "C" void kernel_launch(void* const* d_in, const int* in_sizes, int n_in,
                              void* d_out, int out_size, void* d_ws, size_t ws_size,
                              hipStream_t stream) {
  const float* x  = (const float*)d_in[0];
  const float* cw = (const float*)d_in[1];
  const float* cb = (const float*)d_in[2];
  float* out = (float*)d_out;

  unsigned short* apk = (unsigned short*)d_ws;                       // 147456 B
  float*          pb  = (float*)((char*)d_ws + 16 * 9 * 64 * 8 * 2); // 65536 B

  kpn_prepack<<<288, 256, 0, stream>>>(cw, cb, apk, pb);

  dim3 grid(IMG / 16, IMG / 16, 4);   // (16, 16, 4)
  kpn_mfma_kernel<<<grid, 256, 0, stream>>>(x, apk, pb, out);
}

// Round 5
// 146.741 us; speedup vs baseline: 4.2463x; 1.1003x over previous
//
#include <hip/hip_runtime.h>

// KPN fused, round 3 kernel (2nd resubmit after broker timeouts): single kernel, zero workspace.
// Wave = c-quad (4 channels), 2 c-pair passes with A-frags register-resident.
// Inner loop: LDS b128 B-frags + mfma_f32_32x32x16_bf16 only (no global loads).
// Softmax: no max-pass; padding rows killed via bias = -1e30 (exp -> 0).

typedef __bf16 bf16x8 __attribute__((ext_vector_type(8)));
typedef float  f32x16 __attribute__((ext_vector_type(16)));
typedef float  f32x4  __attribute__((ext_vector_type(4)));

#define IMG  256
#define C_IN 16

__device__ __forceinline__ unsigned short f2bf(float f) {
  union { float f; unsigned int u; } v; v.f = f;
  unsigned int u = v.u;
  return (unsigned short)((u + 0x7FFFu + ((u >> 16) & 1u)) >> 16);  // RNE
}

__global__ __launch_bounds__(256, 2) void kpn_fused(
    const float* __restrict__ x, const float* __restrict__ cw,
    const float* __restrict__ cb, float* __restrict__ out)
{
  // xcl: channel-last tile for MFMA B-frags, 16B-half XOR-swizzled by pixel parity
  __shared__ unsigned short xclf[20 * 20 * 16];        // 12800 B
  // xep: padded-pitch (18) channel-last tile for epilogue window reads
  __shared__ unsigned short xep[20][20][18];           // 14400 B
  // bias as float2 (c-pair) per D-row; rows >=25 get -1e30 (exp -> 0)
  __shared__ float2 pbl[32][8];                        //  2048 B

  const int tid  = threadIdx.x;
  const int w0   = blockIdx.x * 16;
  const int h0   = blockIdx.y * 16;
  const int nimg = blockIdx.z;

  // ---- bias staging: exactly 256 jobs ----
  {
    int cp = tid & 7, row = tid >> 3;
    float2 v;
    if (row < 25) { v.x = cb[(2 * cp) * 25 + row]; v.y = cb[(2 * cp + 1) * 25 + row]; }
    else          { v.x = -1e30f; v.y = -1e30f; }
    pbl[row][cp] = v;
  }

  // ---- x staging: 16ci x 20rows x 10 float2 = 3200 jobs ----
  char* xclb = (char*)xclf;
  for (int i = tid; i < 3200; i += 256) {
    int ci = i / 200, rem = i % 200, rr = rem / 10, c2 = rem % 10;
    int gh = h0 + rr - 2, gw = w0 + c2 * 2 - 2;        // gw is even
    float vx = 0.f, vy = 0.f;
    if (gh >= 0 && gh < IMG) {
      const float* rowp = x + ((nimg * C_IN + ci) * IMG + gh) * IMG;
      if (gw >= 0 && gw + 1 < IMG) { float2 v = *(const float2*)(rowp + gw); vx = v.x; vy = v.y; }
      else {
        if (gw >= 0 && gw < IMG)         vx = rowp[gw];
        if (gw + 1 >= 0 && gw + 1 < IMG) vy = rowp[gw + 1];
      }
    }
    unsigned short bx = f2bf(vx), by = f2bf(vy);
    int cc = c2 * 2, half = ci >> 3, cil = ci & 7;
    int q0 = rr * 20 + cc, q1 = q0 + 1;
    *(unsigned short*)(xclb + q0 * 32 + ((half ^ (q0 & 1)) << 4) + cil * 2) = bx;
    *(unsigned short*)(xclb + q1 * 32 + ((half ^ (q1 & 1)) << 4) + cil * 2) = by;
    xep[rr][cc][ci] = bx;
    xep[rr][cc + 1][ci] = by;
  }
  __syncthreads();

  const int wave  = tid >> 6;
  const int lane  = tid & 63;
  const int g     = lane >> 5;
  const int n32   = lane & 31;
  const int px    = n32 & 15;
  const int py_in = n32 >> 4;
  const int m     = n32;               // A-frag weight row this lane holds
  const bool mval = (m < 25);

  // epilogue window byte-offsets per D-reg (invalid rows -> safe addr, weight 0)
  int offs[16];
#pragma unroll
  for (int r = 0; r < 16; ++r) {
    int row = 4 * g + (r & 3) + 8 * (r >> 2);
    int du = row / 5, dv = row % 5;
    offs[r] = (row < 25) ? ((du * 20 + dv) * 36) : 0;
  }

  const char* xepb = (const char*)&xep[0][0][0];

  auto epi = [&](const f32x16& A0, const f32x16& A1, int c0, int py) {
    const int cp = c0 >> 1;
    float s0 = 0.f, s1 = 0.f, ws0 = 0.f, ws1 = 0.f;
    const int base = (py * 20 + px) * 36 + c0 * 2;
#pragma unroll
    for (int r = 0; r < 16; ++r) {
      float2 b = pbl[4 * g + (r & 3) + 8 * (r >> 2)][cp];
      float e0 = __expf(A0[r] + b.x);
      float e1 = __expf(A1[r] + b.y);
      s0 += e0; s1 += e1;
      unsigned int u = *(const unsigned int*)(xepb + base + offs[r]);
      union { unsigned int u; float f; } lo, hi;
      lo.u = u << 16; hi.u = u & 0xFFFF0000u;          // bf16 c0 (lo), c0+1 (hi)
      ws0 = fmaf(e0, lo.f, ws0);
      ws1 = fmaf(e1, hi.f, ws1);
    }
    s0 += __shfl_xor(s0, 32); s1 += __shfl_xor(s1, 32);
    ws0 += __shfl_xor(ws0, 32); ws1 += __shfl_xor(ws1, 32);
    const int   ch  = c0 + g;
    const float val = (g == 0) ? (ws0 / s0) : (ws1 / s1);
    out[((nimg * C_IN + ch) * IMG + (h0 + py)) * IMG + (w0 + px)] = val;
  };

  // ---- two c-pair passes ----
  for (int pass = 0; pass < 2; ++pass) {
    const int c0 = wave * 4 + pass * 2;

    // Build A-frags straight from cw: lane's data = 72 contiguous floats.
    bf16x8 af[2][9];
#pragma unroll
    for (int cc = 0; cc < 2; ++cc) {
      const float* wp = cw + (((c0 + cc) * 25 + (mval ? m : 0)) * 144 + g * 72);
      float raw[72];
#pragma unroll
      for (int q = 0; q < 18; ++q) {
        f32x4 v = *(const f32x4*)(wp + q * 4);
        raw[q * 4 + 0] = v[0]; raw[q * 4 + 1] = v[1];
        raw[q * 4 + 2] = v[2]; raw[q * 4 + 3] = v[3];
      }
#pragma unroll
      for (int pos = 0; pos < 9; ++pos) {
        bf16x8 f;
#pragma unroll
        for (int j = 0; j < 8; ++j) {
          unsigned short b = mval ? f2bf(raw[j * 9 + pos]) : (unsigned short)0;
          reinterpret_cast<unsigned short*>(&f)[j] = b;
        }
        af[cc][pos] = f;
      }
    }

    // 4 n-tile pairs: 4 independent 9-deep MFMA chains each
    for (int ntp = 0; ntp < 4; ++ntp) {
      const int pya = ntp * 4 + py_in;
      const int pyb = pya + 2;
      bf16x8 ba[9], bb[9];
#pragma unroll
      for (int kh = 0; kh < 3; ++kh)
#pragma unroll
        for (int kw = 0; kw < 3; ++kw) {
          int qa = (pya + 1 + kh) * 20 + (px + 1 + kw);
          int qb = (pyb + 1 + kh) * 20 + (px + 1 + kw);
          ba[kh * 3 + kw] = *(const bf16x8*)(xclb + qa * 32 + ((g ^ (qa & 1)) << 4));
          bb[kh * 3 + kw] = *(const bf16x8*)(xclb + qb * 32 + ((g ^ (qb & 1)) << 4));
        }
      f32x16 Aa0{}, Aa1{}, Ab0{}, Ab1{};
#pragma unroll
      for (int pos = 0; pos < 9; ++pos) {
        Aa0 = __builtin_amdgcn_mfma_f32_32x32x16_bf16(af[0][pos], ba[pos], Aa0, 0, 0, 0);
        Aa1 = __builtin_amdgcn_mfma_f32_32x32x16_bf16(af[1][pos], ba[pos], Aa1, 0, 0, 0);
        Ab0 = __builtin_amdgcn_mfma_f32_32x32x16_bf16(af[0][pos], bb[pos], Ab0, 0, 0, 0);
        Ab1 = __builtin_amdgcn_mfma_f32_32x32x16_bf16(af[1][pos], bb[pos], Ab1, 0, 0, 0);
      }
      epi(Aa0, Aa1, c0, pya);
      epi(Ab0, Ab1, c0, pyb);
    }
  }
}

extern "C" void kernel_launch(void* const* d_in, const int* in_sizes, int n_in,
                              void* d_out, int out_size, void* d_ws, size_t ws_size,
                              hipStream_t stream) {
  const float* x  = (const float*)d_in[0];
  const float* cw = (const float*)d_in[1];
  const float* cb = (const float*)d_in[2];
  float* out = (float*)d_out;

  dim3 grid(IMG / 16, IMG / 16, 4);   // (16, 16, 4) = 1024 blocks
  kpn_fused<<<grid, 256, 0, stream>>>(x, cw, cb, out);
}

// Round 10
// 117.970 us; speedup vs baseline: 5.2819x; 1.2439x over previous
//
#include <hip/hip_runtime.h>

// KPN fused, round 6 kernel (5th submit; prior four hit broker timeouts).
// - prepack kernel: weights*log2e + bias*log2e (pad rows -1e30) -> MFMA fragment order in d_ws
// - main kernel: per-pixel channel-gather staging (b128 conflict-free writes),
//   channel-pair-planar epilogue tile, bias as C-operand of first MFMA,
//   13-iter epilogue with raw v_exp_f32 (2^x) and rcp.

typedef __bf16 bf16x8 __attribute__((ext_vector_type(8)));
typedef float  f32x16 __attribute__((ext_vector_type(16)));
typedef unsigned int uint4v __attribute__((ext_vector_type(4)));

#define IMG   256
#define C_IN  16
#define LOG2E 1.4426950408889634f

#if __has_builtin(__builtin_amdgcn_exp2f)
#define EXP2(x) __builtin_amdgcn_exp2f(x)
#else
#define EXP2(x) __expf(0.69314718055994531f * (x))
#endif

#if __has_builtin(__builtin_amdgcn_rcpf)
#define RCP(x) __builtin_amdgcn_rcpf(x)
#else
#define RCP(x) (1.0f / (x))
#endif

__device__ __forceinline__ unsigned short f2bf(float f) {
  union { float f; unsigned int u; } v; v.f = f;
  unsigned int u = v.u;
  return (unsigned short)((u + 0x7FFFu + ((u >> 16) & 1u)) >> 16);  // RNE
}

__device__ __forceinline__ unsigned int cvt_pk_bf16(float lo, float hi) {
  unsigned int r;
  asm("v_cvt_pk_bf16_f32 %0, %1, %2" : "=v"(r) : "v"(lo), "v"(hi));
  return r;
}

// ---------------- prepack ----------------
// apk[(c*9+pos)*64+lane] : bf16x8 A-frag, W[c*25+m, ci=8g+j, pos]*LOG2E (m=lane&31, pad rows 0)
// pb [(c*64+lane)]       : f32x16 bias frag, row=(r&3)+8(r>>2)+4g; pad rows -1e30
__global__ __launch_bounds__(256) void kpn_prepack(
    const float* __restrict__ cw, const float* __restrict__ cb,
    unsigned short* __restrict__ apk, float* __restrict__ pb)
{
  int t = blockIdx.x * 256 + threadIdx.x;
  if (t < 16 * 9 * 64) {                       // one thread per (c,pos,lane)
    int lane = t & 63, pc = t >> 6;
    int pos = pc % 9, c = pc / 9;
    int m = lane & 31, g = lane >> 5;
    unsigned short v8[8];
#pragma unroll
    for (int j = 0; j < 8; ++j) {
      int ci = 8 * g + j;
      float v = (m < 25) ? cw[((c * 25 + m) * 16 + ci) * 9 + pos] * LOG2E : 0.f;
      v8[j] = f2bf(v);
    }
    uint4v pk;
    pk[0] = (unsigned)v8[0] | ((unsigned)v8[1] << 16);
    pk[1] = (unsigned)v8[2] | ((unsigned)v8[3] << 16);
    pk[2] = (unsigned)v8[4] | ((unsigned)v8[5] << 16);
    pk[3] = (unsigned)v8[6] | ((unsigned)v8[7] << 16);
    *reinterpret_cast<uint4v*>(apk + t * 8) = pk;
  }
  int tb = t - 16 * 9 * 64;
  if (tb >= 0 && tb < 16 * 64) {               // one thread per (c,lane)
    int lane = tb & 63, c = tb >> 6, g = lane >> 5;
    f32x16 v;
#pragma unroll
    for (int r = 0; r < 16; ++r) {
      int row = (r & 3) + 8 * (r >> 2) + 4 * g;
      v[r] = (row < 25) ? cb[c * 25 + row] * LOG2E : -1e30f;
    }
    *reinterpret_cast<f32x16*>(pb + tb * 16) = v;
  }
}

// ---------------- main fused kernel ----------------
__global__ __launch_bounds__(256, 2) void kpn_main(
    const float* __restrict__ x,
    const unsigned short* __restrict__ apk,
    const float* __restrict__ pb,
    float* __restrict__ out)
{
  // B-frag tile: pixel-major, 32B/pixel (16 ch bf16) -> b128 reads at half g
  __shared__ unsigned int xcl[400 * 8];        // 12800 B
  // epilogue tile: channel-pair planar, u32 = (bf16 c_even | bf16 c_odd<<16), pitch 24
  __shared__ unsigned int ep[8 * 20 * 24];     // 15360 B

  const int tid  = threadIdx.x;
  const int w0   = blockIdx.x * 16;
  const int h0   = blockIdx.y * 16;
  const int nimg = blockIdx.z;

  // ---- staging: one thread per tile pixel, gather all 16 channels ----
  for (int p = tid; p < 400; p += 256) {
    int rr = p / 20, cc = p % 20;
    int gh = h0 + rr - 2, gw = w0 + cc - 2;
    float f[16];
    if (gh >= 0 && gh < IMG && gw >= 0 && gw < IMG) {
      const float* src = x + (size_t)nimg * C_IN * IMG * IMG + gh * IMG + gw;
#pragma unroll
      for (int ci = 0; ci < 16; ++ci) f[ci] = src[ci * IMG * IMG];
    } else {
#pragma unroll
      for (int ci = 0; ci < 16; ++ci) f[ci] = 0.f;
    }
    unsigned int u[8];
#pragma unroll
    for (int k = 0; k < 8; ++k) u[k] = cvt_pk_bf16(f[2 * k], f[2 * k + 1]);
    uint4v* dst = reinterpret_cast<uint4v*>(&xcl[p * 8]);
    uint4v lo, hi;
    lo[0] = u[0]; lo[1] = u[1]; lo[2] = u[2]; lo[3] = u[3];
    hi[0] = u[4]; hi[1] = u[5]; hi[2] = u[6]; hi[3] = u[7];
    dst[0] = lo; dst[1] = hi;
#pragma unroll
    for (int k = 0; k < 8; ++k) ep[k * 480 + rr * 24 + cc] = u[k];
  }
  __syncthreads();

  const int wave  = tid >> 6;
  const int lane  = tid & 63;
  const int g     = lane >> 5;
  const int n32   = lane & 31;
  const int px    = n32 & 15;
  const int py_in = n32 >> 4;

  // epilogue window u32-index offsets per D-reg (r = 0..12; invalid rows -> 0, killed by exp->0)
  int offs[13];
#pragma unroll
  for (int r = 0; r < 13; ++r) {
    int row = 4 * g + (r & 3) + 8 * (r >> 2);
    offs[r] = (row < 25) ? ((row / 5) * 24 + (row % 5)) : 0;
  }

  auto epi = [&](const f32x16& A0, const f32x16& A1, int c0, int py) {
    float s0 = 0.f, s1 = 0.f, ws0 = 0.f, ws1 = 0.f;
    const unsigned int* base = &ep[(c0 >> 1) * 480 + py * 24 + px];
#pragma unroll
    for (int r = 0; r < 13; ++r) {
      float e0 = EXP2(A0[r]);          // logits pre-scaled by log2e; pad rows -> exp2(-1e30)=0
      float e1 = EXP2(A1[r]);
      s0 += e0; s1 += e1;
      unsigned int u = base[offs[r]];
      union { unsigned int u; float f; } lo, hi;
      lo.u = u << 16; hi.u = u & 0xFFFF0000u;       // bf16 c0 (low), c0+1 (high)
      ws0 = fmaf(e0, lo.f, ws0);
      ws1 = fmaf(e1, hi.f, ws1);
    }
    s0 += __shfl_xor(s0, 32);  s1 += __shfl_xor(s1, 32);
    ws0 += __shfl_xor(ws0, 32); ws1 += __shfl_xor(ws1, 32);
    const int   ch  = c0 + g;
    const float val = (g == 0) ? (ws0 * RCP(s0)) : (ws1 * RCP(s1));
    out[(((size_t)nimg * C_IN + ch) * IMG + (h0 + py)) * IMG + (w0 + px)] = val;
  };

  const bf16x8* apv = reinterpret_cast<const bf16x8*>(apk);
  const f32x16* pbv = reinterpret_cast<const f32x16*>(pb);

  for (int pass = 0; pass < 2; ++pass) {
    const int c0 = wave * 4 + pass * 2;

    bf16x8 af0[9], af1[9];
#pragma unroll
    for (int pos = 0; pos < 9; ++pos) {
      af0[pos] = apv[(c0 * 9 + pos) * 64 + lane];
      af1[pos] = apv[((c0 + 1) * 9 + pos) * 64 + lane];
    }
    const f32x16 b0 = pbv[c0 * 64 + lane];
    const f32x16 b1 = pbv[(c0 + 1) * 64 + lane];

    for (int ntp = 0; ntp < 4; ++ntp) {
      const int pya = ntp * 4 + py_in;
      const int pyb = pya + 2;
      bf16x8 ba[9], bb[9];
#pragma unroll
      for (int kh = 0; kh < 3; ++kh)
#pragma unroll
        for (int kw = 0; kw < 3; ++kw) {
          int qa = (pya + 1 + kh) * 20 + (px + 1 + kw);
          int qb = (pyb + 1 + kh) * 20 + (px + 1 + kw);
          ba[kh * 3 + kw] = *reinterpret_cast<const bf16x8*>(&xcl[qa * 8 + g * 4]);
          bb[kh * 3 + kw] = *reinterpret_cast<const bf16x8*>(&xcl[qb * 8 + g * 4]);
        }
      // bias rides in as C-operand of the first MFMA (no init movs, no epilogue adds)
      f32x16 Aa0 = __builtin_amdgcn_mfma_f32_32x32x16_bf16(af0[0], ba[0], b0, 0, 0, 0);
      f32x16 Aa1 = __builtin_amdgcn_mfma_f32_32x32x16_bf16(af1[0], ba[0], b1, 0, 0, 0);
      f32x16 Ab0 = __builtin_amdgcn_mfma_f32_32x32x16_bf16(af0[0], bb[0], b0, 0, 0, 0);
      f32x16 Ab1 = __builtin_amdgcn_mfma_f32_32x32x16_bf16(af1[0], bb[0], b1, 0, 0, 0);
#pragma unroll
      for (int pos = 1; pos < 9; ++pos) {
        Aa0 = __builtin_amdgcn_mfma_f32_32x32x16_bf16(af0[pos], ba[pos], Aa0, 0, 0, 0);
        Aa1 = __builtin_amdgcn_mfma_f32_32x32x16_bf16(af1[pos], ba[pos], Aa1, 0, 0, 0);
        Ab0 = __builtin_amdgcn_mfma_f32_32x32x16_bf16(af0[pos], bb[pos], Ab0, 0, 0, 0);
        Ab1 = __builtin_amdgcn_mfma_f32_32x32x16_bf16(af1[pos], bb[pos], Ab1, 0, 0, 0);
      }
      epi(Aa0, Aa1, c0, pya);
      epi(Ab0, Ab1, c0, pyb);
    }
  }
}

extern "C" void kernel_launch(void* const* d_in, const int* in_sizes, int n_in,
                              void* d_out, int out_size, void* d_ws, size_t ws_size,
                              hipStream_t stream) {
  const float* x  = (const float*)d_in[0];
  const float* cw = (const float*)d_in[1];
  const float* cb = (const float*)d_in[2];
  float* out = (float*)d_out;

  unsigned short* apk = (unsigned short*)d_ws;                        // 147456 B
  float*          pb  = (float*)((char*)d_ws + 16 * 9 * 64 * 8 * 2);  //  65536 B

  kpn_prepack<<<40, 256, 0, stream>>>(cw, cb, apk, pb);

  dim3 grid(IMG / 16, IMG / 16, 4);   // 1024 blocks = 4/CU exactly
  kpn_main<<<grid, 256, 0, stream>>>(x, apk, pb, out);
}